// Round 3
// baseline (268.120 us; speedup 1.0000x reference)
//
#include <hip/hip_runtime.h>
#include <math.h>

// BucketingBBoxCoder decode: 1,048,576 proposals; per proposal 28 f32 cls
// (4 sides x 7 buckets), 28 f32 offsets, 4 f32 box -> 4 f32 bbox + 1 f32 conf.
//
// R1 (per-thread strided loads): 101 us, HBM 18%, VALU 14%.
// R2 (coalesced + LDS transpose): 97 us, identical counters. Conclusion:
// phase-serialized (load burst -> all-wave drain -> compute burst) =>
// DRAM duty cycle ~25% => 1.5 TB/s. R3: software-pipeline tiles per block
// (register double-buffer, prefetch tile k+1 before computing tile k) so
// memory latency overlaps compute inside each wave.

#define TILE 256
#define PAD_ROW 29   // 28 + 1 pad; odd stride -> conflict-free-ish on 32 banks

struct TileRegs {
    float4 c[7];
    float4 o[7];
    float4 pr;
};

__device__ __forceinline__ void load_tile(
    const float4* __restrict__ clsv,
    const float4* __restrict__ offv,
    const float4* __restrict__ prv,
    int tile, int t, TileRegs& R)
{
    const size_t base = (size_t)tile * TILE;
    const float4* cp = clsv + base * 7;
    const float4* op = offv + base * 7;
#pragma unroll
    for (int k = 0; k < 7; ++k) R.c[k] = cp[t + TILE * k];
#pragma unroll
    for (int k = 0; k < 7; ++k) R.o[k] = op[t + TILE * k];
    R.pr = prv[base + t];
}

__device__ __forceinline__ void process_tile(
    float* __restrict__ ldsC, float* __restrict__ ldsO,
    int tile, int t, int p0, int e0,
    const TileRegs& R,
    float* __restrict__ out_bboxes, float* __restrict__ out_conf)
{
    // ---- scatter cls and offs into LDS rows (pad-29) ----
    {
        int p = p0, e = e0;
#pragma unroll
        for (int k = 0; k < 7; ++k) {
            int a = p * PAD_ROW + 4 * e;
            ldsC[a + 0] = R.c[k].x;
            ldsC[a + 1] = R.c[k].y;
            ldsC[a + 2] = R.c[k].z;
            ldsC[a + 3] = R.c[k].w;
            ldsO[a + 0] = R.o[k].x;
            ldsO[a + 1] = R.o[k].y;
            ldsO[a + 2] = R.o[k].z;
            ldsO[a + 3] = R.o[k].w;
            p += 36; e += 4;
            if (e >= 7) { e -= 7; p += 1; }
        }
    }
    __syncthreads();  // B1: writes(k) -> reads(k)

    const int rb = t * PAD_ROW;
    float cls[28];
#pragma unroll
    for (int j = 0; j < 28; ++j) cls[j] = ldsC[rb + j];

    int   lab0s[4];
    float conf_sum = 0.0f;
#pragma unroll
    for (int s = 0; s < 4; ++s) {
        float best0 = cls[s * 7 + 0];
        float best1 = -INFINITY;
        int   lab0 = 0, lab1 = 0;
#pragma unroll
        for (int j = 1; j < 7; ++j) {
            float x = cls[s * 7 + j];
            bool gt0 = x > best0;
            bool gt1 = x > best1;
            // strict > with ascending j => lowest index wins ties (lax.top_k)
            best1 = gt0 ? best0 : (gt1 ? x : best1);
            lab1  = gt0 ? lab0  : (gt1 ? j : lab1);
            best0 = gt0 ? x : best0;
            lab0  = gt0 ? j : lab0;
        }
        float sum = 0.0f;
#pragma unroll
        for (int j = 0; j < 7; ++j) sum += __expf(cls[s * 7 + j] - best0);
        float inv = 1.0f / sum;
        float pA = inv;
        float pB = __expf(best1 - best0) * inv;
        lab0s[s] = lab0;
        conf_sum += pA + pB * (fabsf((float)(lab0 - lab1)) - 1.0f);
    }

    float osel0 = ldsO[rb + 0  + lab0s[0]];
    float osel1 = ldsO[rb + 7  + lab0s[1]];
    float osel2 = ldsO[rb + 14 + lab0s[2]];
    float osel3 = ldsO[rb + 21 + lab0s[3]];

    // ---- geometry + decode ----
    float4 pr = R.pr;
    float cx = (pr.x + pr.z) * 0.5f;
    float cy = (pr.y + pr.w) * 0.5f;
    float pw = (pr.z - pr.x) * 3.0f;
    float ph = (pr.w - pr.y) * 3.0f;
    float px1 = cx - 0.5f * pw, px2 = cx + 0.5f * pw;
    float py1 = cy - 0.5f * ph, py2 = cy + 0.5f * ph;
    float bw = pw / 14.0f, bh = ph / 14.0f;

    float x1 = px1 + (0.5f + (float)lab0s[0]) * bw - osel0 * bw;
    float x2 = px2 - (0.5f + (float)lab0s[1]) * bw - osel1 * bw;
    float y1 = py1 + (0.5f + (float)lab0s[2]) * bh - osel2 * bh;
    float y2 = py2 - (0.5f + (float)lab0s[3]) * bh - osel3 * bh;

    x1 = fminf(fmaxf(x1, 0.0f), 1332.0f);
    x2 = fminf(fmaxf(x2, 0.0f), 1332.0f);
    y1 = fminf(fmaxf(y1, 0.0f), 799.0f);
    y2 = fminf(fmaxf(y2, 0.0f), 799.0f);

    const size_t gid = (size_t)tile * TILE + t;
    reinterpret_cast<float4*>(out_bboxes)[gid] = make_float4(x1, y1, x2, y2);
    out_conf[gid] = conf_sum * 0.25f;

    __syncthreads();  // B2: reads(k) -> writes(k+1)
}

__global__ __launch_bounds__(256) void bucketing_bbox_pipe_kernel(
    const float* __restrict__ proposals,
    const float* __restrict__ cls_preds,
    const float* __restrict__ offset_preds,
    float* __restrict__ out_bboxes,
    float* __restrict__ out_conf,
    int ntiles)
{
    __shared__ float ldsC[TILE * PAD_ROW];  // 29,696 B
    __shared__ float ldsO[TILE * PAD_ROW];  // 29,696 B

    const int t = threadIdx.x;
    int tile = blockIdx.x;
    if (tile >= ntiles) return;  // block-uniform

    const int p0 = t / 7;
    const int e0 = t - p0 * 7;
    const int G = gridDim.x;

    const float4* clsv = reinterpret_cast<const float4*>(cls_preds);
    const float4* offv = reinterpret_cast<const float4*>(offset_preds);
    const float4* prv  = reinterpret_cast<const float4*>(proposals);

    TileRegs RA, RB;
    load_tile(clsv, offv, prv, tile, t, RA);

    for (;;) {
        // A phase: prefetch next into B, compute current from A
        int tn = tile + G;
        bool hn = (tn < ntiles);
        if (hn) load_tile(clsv, offv, prv, tn, t, RB);
        process_tile(ldsC, ldsO, tile, t, p0, e0, RA, out_bboxes, out_conf);
        if (!hn) break;
        tile = tn;

        // B phase: prefetch next into A, compute current from B
        tn = tile + G;
        hn = (tn < ntiles);
        if (hn) load_tile(clsv, offv, prv, tn, t, RA);
        process_tile(ldsC, ldsO, tile, t, p0, e0, RB, out_bboxes, out_conf);
        if (!hn) break;
        tile = tn;
    }
}

// Tail fallback for total % 256 != 0 (not hit for this shape).
__global__ __launch_bounds__(256) void bucketing_bbox_tail_kernel(
    const float* __restrict__ proposals,
    const float* __restrict__ cls_preds,
    const float* __restrict__ offset_preds,
    float* __restrict__ out_bboxes,
    float* __restrict__ out_conf,
    int start, int total)
{
    int i = start + blockIdx.x * blockDim.x + threadIdx.x;
    if (i >= total) return;

    float4 pr = reinterpret_cast<const float4*>(proposals)[i];
    float cls[28], offs[28];
    {
        const float4* cp = reinterpret_cast<const float4*>(cls_preds + (size_t)i * 28);
        const float4* op = reinterpret_cast<const float4*>(offset_preds + (size_t)i * 28);
#pragma unroll
        for (int k = 0; k < 7; ++k) reinterpret_cast<float4*>(cls)[k] = cp[k];
#pragma unroll
        for (int k = 0; k < 7; ++k) reinterpret_cast<float4*>(offs)[k] = op[k];
    }
    float cx = (pr.x + pr.z) * 0.5f;
    float cy = (pr.y + pr.w) * 0.5f;
    float pw = (pr.z - pr.x) * 3.0f;
    float ph = (pr.w - pr.y) * 3.0f;
    float px1 = cx - 0.5f * pw, px2 = cx + 0.5f * pw;
    float py1 = cy - 0.5f * ph, py2 = cy + 0.5f * ph;
    float bw = pw / 14.0f, bh = ph / 14.0f;

    int lab0s[4]; float offsel[4]; float conf_sum = 0.0f;
#pragma unroll
    for (int s = 0; s < 4; ++s) {
        float best0 = cls[s * 7], best1 = -INFINITY;
        int lab0 = 0, lab1 = 0;
        float osel = offs[s * 7];
#pragma unroll
        for (int j = 1; j < 7; ++j) {
            float x = cls[s * 7 + j], o = offs[s * 7 + j];
            bool gt0 = x > best0, gt1 = x > best1;
            best1 = gt0 ? best0 : (gt1 ? x : best1);
            lab1  = gt0 ? lab0  : (gt1 ? j : lab1);
            best0 = gt0 ? x : best0;
            lab0  = gt0 ? j : lab0;
            osel  = gt0 ? o : osel;
        }
        float sum = 0.0f;
#pragma unroll
        for (int j = 0; j < 7; ++j) sum += __expf(cls[s * 7 + j] - best0);
        float inv = 1.0f / sum;
        lab0s[s] = lab0; offsel[s] = osel;
        conf_sum += inv + __expf(best1 - best0) * inv * (fabsf((float)(lab0 - lab1)) - 1.0f);
    }
    float x1 = px1 + (0.5f + (float)lab0s[0]) * bw - offsel[0] * bw;
    float x2 = px2 - (0.5f + (float)lab0s[1]) * bw - offsel[1] * bw;
    float y1 = py1 + (0.5f + (float)lab0s[2]) * bh - offsel[2] * bh;
    float y2 = py2 - (0.5f + (float)lab0s[3]) * bh - offsel[3] * bh;
    x1 = fminf(fmaxf(x1, 0.0f), 1332.0f);
    x2 = fminf(fmaxf(x2, 0.0f), 1332.0f);
    y1 = fminf(fmaxf(y1, 0.0f), 799.0f);
    y2 = fminf(fmaxf(y2, 0.0f), 799.0f);
    reinterpret_cast<float4*>(out_bboxes)[i] = make_float4(x1, y1, x2, y2);
    out_conf[i] = conf_sum * 0.25f;
}

extern "C" void kernel_launch(void* const* d_in, const int* in_sizes, int n_in,
                              void* d_out, int out_size, void* d_ws, size_t ws_size,
                              hipStream_t stream) {
    const float* proposals    = (const float*)d_in[0];
    const float* cls_preds    = (const float*)d_in[1];
    const float* offset_preds = (const float*)d_in[2];

    int total = in_sizes[0] / 4;  // B*N proposals (1,048,576)

    float* out_bboxes = (float*)d_out;                       // total*4
    float* out_conf   = (float*)d_out + (size_t)total * 4;   // total

    int ntiles = total / TILE;   // 4096 for this shape
    int rem = total - ntiles * TILE;

    if (ntiles > 0) {
        int grid = ntiles < 1024 ? ntiles : 1024;
        bucketing_bbox_pipe_kernel<<<grid, TILE, 0, stream>>>(
            proposals, cls_preds, offset_preds, out_bboxes, out_conf, ntiles);
    }
    if (rem > 0) {
        int start = ntiles * TILE;
        bucketing_bbox_tail_kernel<<<(rem + 255) / 256, 256, 0, stream>>>(
            proposals, cls_preds, offset_preds, out_bboxes, out_conf, start, total);
    }
}

// Round 5
// 267.682 us; speedup vs baseline: 1.0016x; 1.0016x over previous
//
#include <hip/hip_runtime.h>
#include <math.h>

// BucketingBBoxCoder decode: 1,048,576 proposals; 28 f32 cls (4 sides x 7
// buckets), 28 f32 offsets, 4 f32 box -> 4 f32 bbox + 1 f32 conf.
//
// History: R1 (per-thread strided) / R2 (coalesced+LDS) / R3 ("pipelined",
// defeated by compiler) ALL = ~100 us, ~2.5 TB/s read rate, occupancy
// 17-59% with zero effect. Model: per-CU read-stream ceiling. Lever: read
// BYTES. R5 (=R4 fixed): gather exactly the 4 needed offset dwords after
// the top-2 scan (requested bytes 252 -> 156 MB). NT loads for the
// zero-reuse streams (native vector type required by the builtin),
// cached loads for gathers (adjacent lanes share lines).

typedef float v4f __attribute__((ext_vector_type(4)));

__global__ __launch_bounds__(256) void bucketing_bbox_gather_kernel(
    const float* __restrict__ proposals,
    const float* __restrict__ cls_preds,
    const float* __restrict__ offset_preds,
    float* __restrict__ out_bboxes,
    float* __restrict__ out_conf,
    int total)
{
    int i = blockIdx.x * blockDim.x + threadIdx.x;
    if (i >= total) return;

    // ---- streaming loads: 7x v4f cls + 1x v4f proposal (nontemporal) ----
    const v4f* cp = reinterpret_cast<const v4f*>(cls_preds) + (size_t)i * 7;
    v4f c[7];
#pragma unroll
    for (int k = 0; k < 7; ++k) c[k] = __builtin_nontemporal_load(cp + k);
    v4f pr = __builtin_nontemporal_load(
        reinterpret_cast<const v4f*>(proposals) + i);

    float cls[28];
#pragma unroll
    for (int k = 0; k < 7; ++k) {
        cls[4 * k + 0] = c[k].x;
        cls[4 * k + 1] = c[k].y;
        cls[4 * k + 2] = c[k].z;
        cls[4 * k + 3] = c[k].w;
    }

    // ---- pass 1: top-2 scan per side (labels only; exp deferred) ----
    int   lab0s[4], lab1s[4];
    float best0s[4], best1s[4];
#pragma unroll
    for (int s = 0; s < 4; ++s) {
        float best0 = cls[s * 7 + 0];
        float best1 = -INFINITY;
        int   lab0 = 0, lab1 = 0;
#pragma unroll
        for (int j = 1; j < 7; ++j) {
            float x = cls[s * 7 + j];
            bool gt0 = x > best0;
            bool gt1 = x > best1;
            // strict > with ascending j => lowest index wins ties (lax.top_k)
            best1 = gt0 ? best0 : (gt1 ? x : best1);
            lab1  = gt0 ? lab0  : (gt1 ? j : lab1);
            best0 = gt0 ? x : best0;
            lab0  = gt0 ? j : lab0;
        }
        lab0s[s] = lab0; lab1s[s] = lab1;
        best0s[s] = best0; best1s[s] = best1;
    }

    // ---- issue the 4 offset gathers NOW (latency hidden under softmax) ----
    const float* ob = offset_preds + (size_t)i * 28;
    float osel0 = ob[0  + lab0s[0]];
    float osel1 = ob[7  + lab0s[1]];
    float osel2 = ob[14 + lab0s[2]];
    float osel3 = ob[21 + lab0s[3]];

    // ---- pass 2: softmax sums + confidence (independent of gathers) ----
    float conf_sum = 0.0f;
#pragma unroll
    for (int s = 0; s < 4; ++s) {
        float best0 = best0s[s];
        float sum = 0.0f;
#pragma unroll
        for (int j = 0; j < 7; ++j) sum += __expf(cls[s * 7 + j] - best0);
        float inv = 1.0f / sum;
        float pA = inv;                               // exp(0)/sum
        float pB = __expf(best1s[s] - best0) * inv;
        float neighbor = fabsf((float)(lab0s[s] - lab1s[s])) - 1.0f;
        conf_sum += pA + pB * neighbor;
    }

    // ---- geometry + decode ----
    float cx = (pr.x + pr.z) * 0.5f;
    float cy = (pr.y + pr.w) * 0.5f;
    float pw = (pr.z - pr.x) * 3.0f;
    float ph = (pr.w - pr.y) * 3.0f;
    float px1 = cx - 0.5f * pw, px2 = cx + 0.5f * pw;
    float py1 = cy - 0.5f * ph, py2 = cy + 0.5f * ph;
    float bw = pw / 14.0f, bh = ph / 14.0f;

    float x1 = px1 + (0.5f + (float)lab0s[0]) * bw - osel0 * bw;
    float x2 = px2 - (0.5f + (float)lab0s[1]) * bw - osel1 * bw;
    float y1 = py1 + (0.5f + (float)lab0s[2]) * bh - osel2 * bh;
    float y2 = py2 - (0.5f + (float)lab0s[3]) * bh - osel3 * bh;

    x1 = fminf(fmaxf(x1, 0.0f), 1332.0f);  // W-1
    x2 = fminf(fmaxf(x2, 0.0f), 1332.0f);
    y1 = fminf(fmaxf(y1, 0.0f), 799.0f);   // H-1
    y2 = fminf(fmaxf(y2, 0.0f), 799.0f);

    v4f box;
    box.x = x1; box.y = y1; box.z = x2; box.w = y2;
    __builtin_nontemporal_store(box, reinterpret_cast<v4f*>(out_bboxes) + i);
    __builtin_nontemporal_store(conf_sum * 0.25f, out_conf + i);
}

extern "C" void kernel_launch(void* const* d_in, const int* in_sizes, int n_in,
                              void* d_out, int out_size, void* d_ws, size_t ws_size,
                              hipStream_t stream) {
    const float* proposals    = (const float*)d_in[0];
    const float* cls_preds    = (const float*)d_in[1];
    const float* offset_preds = (const float*)d_in[2];

    int total = in_sizes[0] / 4;  // B*N proposals (1,048,576)

    float* out_bboxes = (float*)d_out;                       // total*4
    float* out_conf   = (float*)d_out + (size_t)total * 4;   // total

    int block = 256;
    int grid = (total + block - 1) / block;
    bucketing_bbox_gather_kernel<<<grid, block, 0, stream>>>(
        proposals, cls_preds, offset_preds, out_bboxes, out_conf, total);
}